// Round 1
// 324.503 us; speedup vs baseline: 1.0799x; 1.0799x over previous
//
#include <hip/hip_runtime.h>
#include <math.h>

#define H 768
#define LN_EPS 1e-5f

typedef float nfloat4 __attribute__((ext_vector_type(4)));  // native vec for nontemporal store

// -------------------------------------------------------------------------
// Shared geometry-feature computation (must stay bit-identical between the
// stats kernel and the main kernel so LN stats match the matmul inputs).
// -------------------------------------------------------------------------
__device__ __forceinline__ void geo_feats(
    const float4 bx,
    const float tx0, const float ty0, const float tx1, const float ty1,
    const float w1, const float h1, const float c1x, const float c1y,
    const float a1, const float ra1,
    float* __restrict__ v)
{
    const float tanA = 0.41421356237309503f;       // tan(22.5 deg)
    const float tanB = 2.41421356237309503f;       // tan(67.5 deg)
    const float x0 = bx.x, y0 = bx.y, x1 = bx.z, y1 = bx.w;
    const float w2 = x1 - x0, h2 = y1 - y0;
    v[0] = w2; v[1] = h2;
    v[2] = fabsf(w1 - w2); v[3] = fabsf(h1 - h2);
    const float c2x = (x0 + x1) * 0.5f, c2y = (y0 + y1) * 0.5f;
    const float dx = c2x - c1x, dy = c2y - c1y;
    v[4] = __builtin_amdgcn_sqrtf(dx * dx + dy * dy);
    const bool overlap = (tx0 < x1) && (tx1 > x0) && (ty0 < y1) && (ty1 > y0);
    const float xi0 = fmaxf(tx0, x0), yi0 = fmaxf(ty0, y0);
    const float xi1 = fminf(tx1, x1), yi1 = fminf(ty1, y1);
    const float inter = overlap ? (xi1 - xi0) * (yi1 - yi0) : 0.0f;
    const float a2 = w2 * h2;
    const float uni = a1 + a2 - inter;
    v[5] = inter * __builtin_amdgcn_rcpf(uni);
    v[6] = inter * ra1;
    v[7] = inter * __builtin_amdgcn_rcpf(a2);
    const float adx = fabsf(dx), ady = fabsf(dy);
    v[8] = (ady > adx * tanA) ? ((ady > adx * tanB) ? 2.0f : 1.0f) : 8.0f;
}

// -------------------------------------------------------------------------
// Kernel A1: Gram matrix G = W12 * W12^T / H (12x12) and row means m (12),
// where W12 = [W (11 x H); bias (1 x H)].  ws[0..143]=G, ws[144..155]=m.
// Grid: 90 blocks (78 unique pairs p>=q, 12 means), 256 threads each.
// -------------------------------------------------------------------------
__global__ __launch_bounds__(256) void gram_kernel(
    const float* __restrict__ W,
    const float* __restrict__ bias,
    float* __restrict__ ws)
{
    const int i = blockIdx.x;
    const int tid = threadIdx.x;

    int p = 0, q = 0;
    const float* A;
    const float* B = nullptr;
    if (i < 78) {                       // triangular decode: i = p(p+1)/2 + q
        while ((p + 1) * (p + 2) / 2 <= i) ++p;
        q = i - p * (p + 1) / 2;
        A = (p < 11) ? (W + p * H) : bias;
        B = (q < 11) ? (W + q * H) : bias;
    } else {
        p = i - 78;
        A = (p < 11) ? (W + p * H) : bias;
    }

    float acc = 0.0f;
    if (B) {
        for (int c = tid; c < H; c += 256) acc += A[c] * B[c];
    } else {
        for (int c = tid; c < H; c += 256) acc += A[c];
    }

    #pragma unroll
    for (int off = 32; off >= 1; off >>= 1) acc += __shfl_xor(acc, off, 64);

    __shared__ float red[4];
    if ((tid & 63) == 0) red[tid >> 6] = acc;
    __syncthreads();
    if (tid == 0) {
        const float s = ((red[0] + red[1]) + (red[2] + red[3])) * (1.0f / H);
        if (i < 78) { ws[p * 12 + q] = s; ws[q * 12 + p] = s; }
        else        { ws[144 + p] = s; }
    }
}

// -------------------------------------------------------------------------
// Kernel A2: per-box LN stats via the Gram quadratic form.
//   mean = mconst + sum_k mlin[k] v[k]
//   E[x^2] = K + sum_l v_l (qlin_l + sum_k Q[l][k] v_k)
//   stats[b] = { rstd, mean*rstd }
// One box per thread, coalesced box loads; Q/qlin folded from G + target.
// -------------------------------------------------------------------------
__global__ __launch_bounds__(256) void stats_kernel(
    const float* __restrict__ target,
    const float* __restrict__ boxes,
    const float* __restrict__ ws,
    float2* __restrict__ stats,
    int N)
{
    const float tx0 = target[0], ty0 = target[1], tx1 = target[2], ty1 = target[3];
    const float w1 = tx1 - tx0, h1 = ty1 - ty0;
    const float c1x = (tx0 + tx1) * 0.5f, c1y = (ty0 + ty1) * 0.5f;
    const float a1 = w1 * h1;
    const float ra1 = 1.0f / a1;

    // fold target constants into the 9-var quadratic
    float Q[9][9], qlin[9], mlin[9];
    #pragma unroll
    for (int l = 0; l < 9; ++l)
        #pragma unroll
        for (int k = 0; k < 9; ++k)
            Q[l][k] = ws[(l + 2) * 12 + (k + 2)];
    #pragma unroll
    for (int k = 0; k < 9; ++k) {
        qlin[k] = 2.0f * (w1 * ws[0 * 12 + (k + 2)]
                        + h1 * ws[1 * 12 + (k + 2)]
                        +      ws[11 * 12 + (k + 2)]);
        mlin[k] = ws[144 + k + 2];
    }
    const float K = w1 * w1 * ws[0] + 2.0f * w1 * h1 * ws[1] + h1 * h1 * ws[13]
                  + 2.0f * w1 * ws[11] + 2.0f * h1 * ws[1 * 12 + 11] + ws[11 * 12 + 11];
    const float mconst = w1 * ws[144] + h1 * ws[145] + ws[155];

    const float4* __restrict__ boxes4 = reinterpret_cast<const float4*>(boxes);
    const int stride = gridDim.x * blockDim.x;
    for (int b = blockIdx.x * blockDim.x + threadIdx.x; b < N; b += stride) {
        const float4 bx = boxes4[b];
        float v[9];
        geo_feats(bx, tx0, ty0, tx1, ty1, w1, h1, c1x, c1y, a1, ra1, v);

        float mean = mconst;
        #pragma unroll
        for (int k = 0; k < 9; ++k) mean = fmaf(mlin[k], v[k], mean);

        float E = K;
        #pragma unroll
        for (int l = 0; l < 9; ++l) {
            float t = qlin[l];
            #pragma unroll
            for (int k = 0; k < 9; ++k) t = fmaf(Q[l][k], v[k], t);
            E = fmaf(t, v[l], E);
        }

        const float var  = fmaf(-mean, mean, E);
        const float rstd = __builtin_amdgcn_rsqf(fmaxf(var, 0.0f) + LN_EPS);
        float2 st; st.x = rstd; st.y = mean * rstd;
        stats[b] = st;
    }
}

// -------------------------------------------------------------------------
// Main kernel: matmul + LN apply. No cross-lane ops at all (stats are
// precomputed), epilogue is 3 ops/col, 2-pair load prefetch hides L2
// latency of the wave-uniform box/stat loads under the previous pair's FMAs.
// -------------------------------------------------------------------------
__global__ __launch_bounds__(256, 2) void geo_ln_kernel(
    const float* __restrict__ target,
    const float* __restrict__ boxes,
    const float* __restrict__ W,
    const float* __restrict__ bias,
    const float* __restrict__ gamma,
    const float* __restrict__ beta,
    const float2* __restrict__ stats,
    float* __restrict__ out,
    int N)
{
    const int lane = threadIdx.x & 63;
    const int wid  = (blockIdx.x << 2) | (threadIdx.x >> 6);
    const int nw   = gridDim.x << 2;

    const float tx0 = target[0], ty0 = target[1], tx1 = target[2], ty1 = target[3];
    const float w1 = tx1 - tx0, h1 = ty1 - ty0;
    const float c1x = (tx0 + tx1) * 0.5f, c1y = (ty0 + ty1) * 0.5f;
    const float a1 = w1 * h1;
    const float ra1 = 1.0f / a1;

    const float4* __restrict__ W4  = reinterpret_cast<const float4*>(W);
    const float4* __restrict__ b4  = reinterpret_cast<const float4*>(bias);
    const float4* __restrict__ g4  = reinterpret_cast<const float4*>(gamma);
    const float4* __restrict__ be4 = reinterpret_cast<const float4*>(beta);
    const float4* __restrict__ boxes4 = reinterpret_cast<const float4*>(boxes);
    nfloat4* __restrict__ outv = reinterpret_cast<nfloat4*>(out);

    // ---- per-lane resident state: 12 columns (3 x float4) ----
    float4 base[3], Wr[3][9], gm[3], bt[3];
    #pragma unroll
    for (int r = 0; r < 3; ++r) {
        const int c4 = lane + 64 * r;
        float4 acc = b4[c4];
        const float4 w0  = W4[0 * (H / 4) + c4];
        const float4 w1r = W4[1 * (H / 4) + c4];
        acc.x = fmaf(w1, w0.x, acc.x); acc.y = fmaf(w1, w0.y, acc.y);
        acc.z = fmaf(w1, w0.z, acc.z); acc.w = fmaf(w1, w0.w, acc.w);
        acc.x = fmaf(h1, w1r.x, acc.x); acc.y = fmaf(h1, w1r.y, acc.y);
        acc.z = fmaf(h1, w1r.z, acc.z); acc.w = fmaf(h1, w1r.w, acc.w);
        base[r] = acc;
        #pragma unroll
        for (int k = 0; k < 9; ++k)
            Wr[r][k] = W4[(k + 2) * (H / 4) + c4];
        gm[r] = g4[c4];
        bt[r] = be4[c4];
    }

    auto process = [&](const float4 bx, const float2 st, const int box) {
        float v[9];
        geo_feats(bx, tx0, ty0, tx1, ty1, w1, h1, c1x, c1y, a1, ra1, v);
        const float rstd = st.x;
        const float nmr  = -st.y;          // -(mean*rstd)
        nfloat4* __restrict__ orow = outv + (size_t)box * (H / 4);
        #pragma unroll
        for (int r = 0; r < 3; ++r) {
            float4 acc = base[r];
            #pragma unroll
            for (int k = 0; k < 9; ++k) {
                const float4 w = Wr[r][k];
                acc.x = fmaf(v[k], w.x, acc.x);
                acc.y = fmaf(v[k], w.y, acc.y);
                acc.z = fmaf(v[k], w.z, acc.z);
                acc.w = fmaf(v[k], w.w, acc.w);
            }
            const float4 g = gm[r], be = bt[r];
            nfloat4 o;
            o.x = fmaxf(0.0f, fmaf(fmaf(acc.x, rstd, nmr), g.x, be.x));
            o.y = fmaxf(0.0f, fmaf(fmaf(acc.y, rstd, nmr), g.y, be.y));
            o.z = fmaxf(0.0f, fmaf(fmaf(acc.z, rstd, nmr), g.z, be.z));
            o.w = fmaxf(0.0f, fmaf(fmaf(acc.w, rstd, nmr), g.w, be.w));
            __builtin_nontemporal_store(o, &orow[lane + 64 * r]);
        }
    };

    // ---- box loop: two boxes in flight + next-pair prefetch ----
    int box = wid;
    if (box >= N) return;
    float4 bA = boxes4[box];
    float2 sA = stats[box];
    bool hasB = (box + nw < N);
    float4 bB = bA; float2 sB = sA;
    if (hasB) { bB = boxes4[box + nw]; sB = stats[box + nw]; }

    while (hasB) {
        const int nxt = box + 2 * nw;
        const bool hA = (nxt < N), hB = (nxt + nw < N);
        float4 nA = bA, nB = bB; float2 nsA = sA, nsB = sB;
        if (hA) { nA = boxes4[nxt];      nsA = stats[nxt]; }
        if (hB) { nB = boxes4[nxt + nw]; nsB = stats[nxt + nw]; }
        process(bA, sA, box);
        process(bB, sB, box + nw);
        bA = nA; sA = nsA; bB = nB; sB = nsB;
        box = nxt; hasB = hB;
    }
    if (box < N) process(bA, sA, box);
}

// -------------------------------------------------------------------------
// Fallback (previous best kernel, in-wave LN reduction) for the case the
// workspace is too small for the stats path.
// -------------------------------------------------------------------------
__global__ __launch_bounds__(256, 2) void geo_ln_fallback(
    const float* __restrict__ target,
    const float* __restrict__ boxes,
    const float* __restrict__ W,
    const float* __restrict__ bias,
    const float* __restrict__ gamma,
    const float* __restrict__ beta,
    float* __restrict__ out,
    int N)
{
    const int lane = threadIdx.x & 63;
    const int wid  = (blockIdx.x << 2) | (threadIdx.x >> 6);
    const int nw   = gridDim.x << 2;

    const float tx0 = target[0], ty0 = target[1], tx1 = target[2], ty1 = target[3];
    const float w1 = tx1 - tx0, h1 = ty1 - ty0;
    const float c1x = (tx0 + tx1) * 0.5f, c1y = (ty0 + ty1) * 0.5f;
    const float a1 = w1 * h1;
    const float ra1 = 1.0f / a1;

    const float4* __restrict__ W4  = reinterpret_cast<const float4*>(W);
    const float4* __restrict__ b4  = reinterpret_cast<const float4*>(bias);
    const float4* __restrict__ g4  = reinterpret_cast<const float4*>(gamma);
    const float4* __restrict__ be4 = reinterpret_cast<const float4*>(beta);
    const float4* __restrict__ boxes4 = reinterpret_cast<const float4*>(boxes);
    nfloat4* __restrict__ outv = reinterpret_cast<nfloat4*>(out);

    float4 base[3], Wr[3][9], gm[3], bt[3];
    #pragma unroll
    for (int r = 0; r < 3; ++r) {
        const int c4 = lane + 64 * r;
        float4 acc = b4[c4];
        const float4 w0  = W4[0 * (H / 4) + c4];
        const float4 w1r = W4[1 * (H / 4) + c4];
        acc.x = fmaf(w1, w0.x, acc.x); acc.y = fmaf(w1, w0.y, acc.y);
        acc.z = fmaf(w1, w0.z, acc.z); acc.w = fmaf(w1, w0.w, acc.w);
        acc.x = fmaf(h1, w1r.x, acc.x); acc.y = fmaf(h1, w1r.y, acc.y);
        acc.z = fmaf(h1, w1r.z, acc.z); acc.w = fmaf(h1, w1r.w, acc.w);
        base[r] = acc;
        #pragma unroll
        for (int k = 0; k < 9; ++k)
            Wr[r][k] = W4[(k + 2) * (H / 4) + c4];
        gm[r] = g4[c4];
        bt[r] = be4[c4];
    }

    auto process = [&](int box) {
        const float4 bx = boxes4[box];
        float v[9];
        geo_feats(bx, tx0, ty0, tx1, ty1, w1, h1, c1x, c1y, a1, ra1, v);

        float4 xv[3];
        float s = 0.0f, sq = 0.0f;
        #pragma unroll
        for (int r = 0; r < 3; ++r) {
            float4 acc = base[r];
            #pragma unroll
            for (int k = 0; k < 9; ++k) {
                const float4 w = Wr[r][k];
                acc.x = fmaf(v[k], w.x, acc.x);
                acc.y = fmaf(v[k], w.y, acc.y);
                acc.z = fmaf(v[k], w.z, acc.z);
                acc.w = fmaf(v[k], w.w, acc.w);
            }
            xv[r] = acc;
            s  += acc.x + acc.y + acc.z + acc.w;
            sq += acc.x * acc.x + acc.y * acc.y + acc.z * acc.z + acc.w * acc.w;
        }

        #pragma unroll
        for (int off = 32; off >= 1; off >>= 1) {
            s  += __shfl_xor(s,  off, 64);
            sq += __shfl_xor(sq, off, 64);
        }
        const float mean = s * (1.0f / H);
        const float var  = sq * (1.0f / H) - mean * mean;
        const float rstd = __builtin_amdgcn_rsqf(var + LN_EPS);

        nfloat4* __restrict__ orow = outv + (size_t)box * (H / 4);
        #pragma unroll
        for (int r = 0; r < 3; ++r) {
            const float4 vx = xv[r];
            const float4 g = gm[r], be = bt[r];
            nfloat4 o;
            o.x = fmaxf(0.0f, (vx.x - mean) * rstd * g.x + be.x);
            o.y = fmaxf(0.0f, (vx.y - mean) * rstd * g.y + be.y);
            o.z = fmaxf(0.0f, (vx.z - mean) * rstd * g.z + be.z);
            o.w = fmaxf(0.0f, (vx.w - mean) * rstd * g.w + be.w);
            __builtin_nontemporal_store(o, &orow[lane + 64 * r]);
        }
    };

    int box = wid;
    for (; box + nw < N; box += 2 * nw) {
        process(box);
        process(box + nw);
    }
    if (box < N) process(box);
}

extern "C" void kernel_launch(void* const* d_in, const int* in_sizes, int n_in,
                              void* d_out, int out_size, void* d_ws, size_t ws_size,
                              hipStream_t stream) {
    const float* target = (const float*)d_in[0];
    const float* boxes  = (const float*)d_in[1];
    const float* W      = (const float*)d_in[2];
    const float* bias   = (const float*)d_in[3];
    const float* gamma  = (const float*)d_in[4];
    const float* beta   = (const float*)d_in[5];
    float* out = (float*)d_out;

    const int N = in_sizes[1] / 4;   // ocr_boxes is (N, 4)

    // ws layout (floats): [0..143] G, [144..155] row means, [160..] float2 stats
    const size_t needed = (160 + 2 * (size_t)N) * sizeof(float);

    if (d_ws && ws_size >= needed && N > 0) {
        float* wsf = (float*)d_ws;
        float2* stats = (float2*)(wsf + 160);

        gram_kernel<<<90, 256, 0, stream>>>(W, bias, wsf);

        int blocksA2 = (N + 255) / 256;
        if (blocksA2 > 2048) blocksA2 = 2048;
        stats_kernel<<<blocksA2, 256, 0, stream>>>(target, boxes, wsf, stats, N);

        geo_ln_kernel<<<512, 256, 0, stream>>>(target, boxes, W, bias, gamma, beta,
                                               stats, out, N);
    } else {
        geo_ln_fallback<<<512, 256, 0, stream>>>(target, boxes, W, bias, gamma, beta,
                                                 out, N);
    }
}

// Round 2
// 321.847 us; speedup vs baseline: 1.0888x; 1.0083x over previous
//
#include <hip/hip_runtime.h>
#include <math.h>

#define H 768
#define LN_EPS 1e-5f
#define NTRIP 2048            // box-stream triples for the main kernel

typedef float nfloat4 __attribute__((ext_vector_type(4)));  // native vec for nontemporal store

// -------------------------------------------------------------------------
// Shared geometry-feature computation (must stay bit-identical between the
// stats kernel and the main kernel so LN stats match the matmul inputs).
// -------------------------------------------------------------------------
__device__ __forceinline__ void geo_feats(
    const float4 bx,
    const float tx0, const float ty0, const float tx1, const float ty1,
    const float w1, const float h1, const float c1x, const float c1y,
    const float a1, const float ra1,
    float* __restrict__ v)
{
    const float tanA = 0.41421356237309503f;       // tan(22.5 deg)
    const float tanB = 2.41421356237309503f;       // tan(67.5 deg)
    const float x0 = bx.x, y0 = bx.y, x1 = bx.z, y1 = bx.w;
    const float w2 = x1 - x0, h2 = y1 - y0;
    v[0] = w2; v[1] = h2;
    v[2] = fabsf(w1 - w2); v[3] = fabsf(h1 - h2);
    const float c2x = (x0 + x1) * 0.5f, c2y = (y0 + y1) * 0.5f;
    const float dx = c2x - c1x, dy = c2y - c1y;
    v[4] = __builtin_amdgcn_sqrtf(dx * dx + dy * dy);
    const bool overlap = (tx0 < x1) && (tx1 > x0) && (ty0 < y1) && (ty1 > y0);
    const float xi0 = fmaxf(tx0, x0), yi0 = fmaxf(ty0, y0);
    const float xi1 = fminf(tx1, x1), yi1 = fminf(ty1, y1);
    const float inter = overlap ? (xi1 - xi0) * (yi1 - yi0) : 0.0f;
    const float a2 = w2 * h2;
    const float uni = a1 + a2 - inter;
    v[5] = inter * __builtin_amdgcn_rcpf(uni);
    v[6] = inter * ra1;
    v[7] = inter * __builtin_amdgcn_rcpf(a2);
    const float adx = fabsf(dx), ady = fabsf(dy);
    v[8] = (ady > adx * tanA) ? ((ady > adx * tanB) ? 2.0f : 1.0f) : 8.0f;
}

// -------------------------------------------------------------------------
// Kernel A1: Gram matrix G = W12 * W12^T / H (12x12) and row means m (12),
// where W12 = [W (11 x H); bias (1 x H)].  ws[0..143]=G, ws[144..155]=m.
// -------------------------------------------------------------------------
__global__ __launch_bounds__(256) void gram_kernel(
    const float* __restrict__ W,
    const float* __restrict__ bias,
    float* __restrict__ ws)
{
    const int i = blockIdx.x;
    const int tid = threadIdx.x;

    int p = 0, q = 0;
    const float* A;
    const float* B = nullptr;
    if (i < 78) {                       // triangular decode: i = p(p+1)/2 + q
        while ((p + 1) * (p + 2) / 2 <= i) ++p;
        q = i - p * (p + 1) / 2;
        A = (p < 11) ? (W + p * H) : bias;
        B = (q < 11) ? (W + q * H) : bias;
    } else {
        p = i - 78;
        A = (p < 11) ? (W + p * H) : bias;
    }

    float acc = 0.0f;
    if (B) {
        for (int c = tid; c < H; c += 256) acc += A[c] * B[c];
    } else {
        for (int c = tid; c < H; c += 256) acc += A[c];
    }

    #pragma unroll
    for (int off = 32; off >= 1; off >>= 1) acc += __shfl_xor(acc, off, 64);

    __shared__ float red[4];
    if ((tid & 63) == 0) red[tid >> 6] = acc;
    __syncthreads();
    if (tid == 0) {
        const float s = ((red[0] + red[1]) + (red[2] + red[3])) * (1.0f / H);
        if (i < 78) { ws[p * 12 + q] = s; ws[q * 12 + p] = s; }
        else        { ws[144 + p] = s; }
    }
}

// -------------------------------------------------------------------------
// Kernel A2: per-box LN stats via the Gram quadratic form.
//   stats[b] = { rstd, mean*rstd }
// -------------------------------------------------------------------------
__global__ __launch_bounds__(256) void stats_kernel(
    const float* __restrict__ target,
    const float* __restrict__ boxes,
    const float* __restrict__ ws,
    float2* __restrict__ stats,
    int N)
{
    const float tx0 = target[0], ty0 = target[1], tx1 = target[2], ty1 = target[3];
    const float w1 = tx1 - tx0, h1 = ty1 - ty0;
    const float c1x = (tx0 + tx1) * 0.5f, c1y = (ty0 + ty1) * 0.5f;
    const float a1 = w1 * h1;
    const float ra1 = 1.0f / a1;

    float Q[9][9], qlin[9], mlin[9];
    #pragma unroll
    for (int l = 0; l < 9; ++l)
        #pragma unroll
        for (int k = 0; k < 9; ++k)
            Q[l][k] = ws[(l + 2) * 12 + (k + 2)];
    #pragma unroll
    for (int k = 0; k < 9; ++k) {
        qlin[k] = 2.0f * (w1 * ws[0 * 12 + (k + 2)]
                        + h1 * ws[1 * 12 + (k + 2)]
                        +      ws[11 * 12 + (k + 2)]);
        mlin[k] = ws[144 + k + 2];
    }
    const float K = w1 * w1 * ws[0] + 2.0f * w1 * h1 * ws[1] + h1 * h1 * ws[13]
                  + 2.0f * w1 * ws[11] + 2.0f * h1 * ws[1 * 12 + 11] + ws[11 * 12 + 11];
    const float mconst = w1 * ws[144] + h1 * ws[145] + ws[155];

    const float4* __restrict__ boxes4 = reinterpret_cast<const float4*>(boxes);
    const int stride = gridDim.x * blockDim.x;
    for (int b = blockIdx.x * blockDim.x + threadIdx.x; b < N; b += stride) {
        const float4 bx = boxes4[b];
        float v[9];
        geo_feats(bx, tx0, ty0, tx1, ty1, w1, h1, c1x, c1y, a1, ra1, v);

        float mean = mconst;
        #pragma unroll
        for (int k = 0; k < 9; ++k) mean = fmaf(mlin[k], v[k], mean);

        float E = K;
        #pragma unroll
        for (int l = 0; l < 9; ++l) {
            float t = qlin[l];
            #pragma unroll
            for (int k = 0; k < 9; ++k) t = fmaf(Q[l][k], v[k], t);
            E = fmaf(t, v[l], E);
        }

        const float var  = fmaf(-mean, mean, E);
        const float rstd = __builtin_amdgcn_rsqf(fmaxf(var, 0.0f) + LN_EPS);
        float2 st; st.x = rstd; st.y = mean * rstd;
        stats[b] = st;
    }
}

// -------------------------------------------------------------------------
// Main kernel, 3-way column split for occupancy.
//   Wave g: trip t = g/3 owns box stream {t, t+NTRIP, ...}; role = g%3 owns
//   64 consecutive float4 columns (c4 = lane + 64*role). Resident weights:
//   9 float4 (36 VGPR) -> ~90 VGPR total -> 4 waves/SIMD (2x prev TLP).
//   Box+stat records are LDS-staged once per wave, so the steady-state loop
//   has ZERO vector loads: ds_read (lgkmcnt) + nt stores (vmcnt) only --
//   no load wait can force a store-queue drain (vmcnt retires in order).
//   One contiguous 1KB nontemporal store per visit.
// -------------------------------------------------------------------------
__global__ __launch_bounds__(256, 4) void geo_ln_main(
    const float* __restrict__ target,
    const float* __restrict__ boxes,
    const float* __restrict__ W,
    const float* __restrict__ bias,
    const float* __restrict__ gamma,
    const float* __restrict__ beta,
    const float2* __restrict__ stats,
    float* __restrict__ out,
    int N)
{
    const int lane = threadIdx.x & 63;
    const int wl   = threadIdx.x >> 6;
    const int g    = (blockIdx.x << 2) | wl;   // global wave id, 0..6143
    const int t    = g / 3;                    // trip id, 0..2047
    const int role = g - 3 * t;                // 0,1,2

    const float tx0 = target[0], ty0 = target[1], tx1 = target[2], ty1 = target[3];
    const float w1 = tx1 - tx0, h1 = ty1 - ty0;
    const float c1x = (tx0 + tx1) * 0.5f, c1y = (ty0 + ty1) * 0.5f;
    const float a1 = w1 * h1;
    const float ra1 = 1.0f / a1;

    const float4* __restrict__ W4  = reinterpret_cast<const float4*>(W);
    const float4* __restrict__ b4  = reinterpret_cast<const float4*>(bias);
    const float4* __restrict__ g4  = reinterpret_cast<const float4*>(gamma);
    const float4* __restrict__ be4 = reinterpret_cast<const float4*>(beta);
    const float4* __restrict__ boxes4 = reinterpret_cast<const float4*>(boxes);
    nfloat4* __restrict__ outv = reinterpret_cast<nfloat4*>(out);

    // ---- per-lane resident state: 4 columns (1 float4) of this role's block
    const int c4 = lane + (role << 6);
    float4 base = b4[c4];
    {
        const float4 w0  = W4[0 * (H / 4) + c4];
        const float4 w1r = W4[1 * (H / 4) + c4];
        base.x = fmaf(w1, w0.x, base.x); base.y = fmaf(w1, w0.y, base.y);
        base.z = fmaf(w1, w0.z, base.z); base.w = fmaf(w1, w0.w, base.w);
        base.x = fmaf(h1, w1r.x, base.x); base.y = fmaf(h1, w1r.y, base.y);
        base.z = fmaf(h1, w1r.z, base.z); base.w = fmaf(h1, w1r.w, base.w);
    }
    float4 Wr[9];
    #pragma unroll
    for (int k = 0; k < 9; ++k) Wr[k] = W4[(k + 2) * (H / 4) + c4];
    const float4 gm = g4[c4];
    const float4 bt = be4[c4];

    // ---- LDS-stage this wave's box/stat records (<=64 boxes per trip) ----
    __shared__ float recs[4][64 * 8];
    const int nb = (t < N) ? ((N - t + NTRIP - 1) / NTRIP) : 0;   // boxes in stream
    for (int l = lane; l < nb; l += 64) {
        const int b = t + l * NTRIP;
        const float4 bx = boxes4[b];
        const float2 st = stats[b];
        float* r = &recs[wl][l * 8];
        r[0] = bx.x; r[1] = bx.y; r[2] = bx.z; r[3] = bx.w;
        r[4] = st.x; r[5] = st.y;
    }
    __syncthreads();

    // ---- steady state: ds_read + VALU + one 1KB nt store per visit ----
    const float* rw = recs[wl];
    nfloat4* op = outv + (size_t)t * (H / 4) + c4;
    const size_t ostep = (size_t)NTRIP * (H / 4);

    #pragma unroll 2
    for (int k = 0; k < nb; ++k) {
        const float4 bx = *reinterpret_cast<const float4*>(rw + k * 8);
        const float rstd = rw[k * 8 + 4];
        const float nmr  = -rw[k * 8 + 5];     // -(mean*rstd)

        float v[9];
        geo_feats(bx, tx0, ty0, tx1, ty1, w1, h1, c1x, c1y, a1, ra1, v);

        float4 acc = base;
        #pragma unroll
        for (int j = 0; j < 9; ++j) {
            const float4 w = Wr[j];
            acc.x = fmaf(v[j], w.x, acc.x);
            acc.y = fmaf(v[j], w.y, acc.y);
            acc.z = fmaf(v[j], w.z, acc.z);
            acc.w = fmaf(v[j], w.w, acc.w);
        }
        nfloat4 o;
        o.x = fmaxf(0.0f, fmaf(fmaf(acc.x, rstd, nmr), gm.x, bt.x));
        o.y = fmaxf(0.0f, fmaf(fmaf(acc.y, rstd, nmr), gm.y, bt.y));
        o.z = fmaxf(0.0f, fmaf(fmaf(acc.z, rstd, nmr), gm.z, bt.z));
        o.w = fmaxf(0.0f, fmaf(fmaf(acc.w, rstd, nmr), gm.w, bt.w));
        __builtin_nontemporal_store(o, op);
        op += ostep;
    }
}

// -------------------------------------------------------------------------
// Fallback (in-wave LN reduction) for ws-too-small or oversized N.
// -------------------------------------------------------------------------
__global__ __launch_bounds__(256, 2) void geo_ln_fallback(
    const float* __restrict__ target,
    const float* __restrict__ boxes,
    const float* __restrict__ W,
    const float* __restrict__ bias,
    const float* __restrict__ gamma,
    const float* __restrict__ beta,
    float* __restrict__ out,
    int N)
{
    const int lane = threadIdx.x & 63;
    const int wid  = (blockIdx.x << 2) | (threadIdx.x >> 6);
    const int nw   = gridDim.x << 2;

    const float tx0 = target[0], ty0 = target[1], tx1 = target[2], ty1 = target[3];
    const float w1 = tx1 - tx0, h1 = ty1 - ty0;
    const float c1x = (tx0 + tx1) * 0.5f, c1y = (ty0 + ty1) * 0.5f;
    const float a1 = w1 * h1;
    const float ra1 = 1.0f / a1;

    const float4* __restrict__ W4  = reinterpret_cast<const float4*>(W);
    const float4* __restrict__ b4  = reinterpret_cast<const float4*>(bias);
    const float4* __restrict__ g4  = reinterpret_cast<const float4*>(gamma);
    const float4* __restrict__ be4 = reinterpret_cast<const float4*>(beta);
    const float4* __restrict__ boxes4 = reinterpret_cast<const float4*>(boxes);
    nfloat4* __restrict__ outv = reinterpret_cast<nfloat4*>(out);

    float4 base[3], Wr[3][9], gm[3], bt[3];
    #pragma unroll
    for (int r = 0; r < 3; ++r) {
        const int c4 = lane + 64 * r;
        float4 acc = b4[c4];
        const float4 w0  = W4[0 * (H / 4) + c4];
        const float4 w1r = W4[1 * (H / 4) + c4];
        acc.x = fmaf(w1, w0.x, acc.x); acc.y = fmaf(w1, w0.y, acc.y);
        acc.z = fmaf(w1, w0.z, acc.z); acc.w = fmaf(w1, w0.w, acc.w);
        acc.x = fmaf(h1, w1r.x, acc.x); acc.y = fmaf(h1, w1r.y, acc.y);
        acc.z = fmaf(h1, w1r.z, acc.z); acc.w = fmaf(h1, w1r.w, acc.w);
        base[r] = acc;
        #pragma unroll
        for (int k = 0; k < 9; ++k)
            Wr[r][k] = W4[(k + 2) * (H / 4) + c4];
        gm[r] = g4[c4];
        bt[r] = be4[c4];
    }

    auto process = [&](int box) {
        const float4 bx = boxes4[box];
        float v[9];
        geo_feats(bx, tx0, ty0, tx1, ty1, w1, h1, c1x, c1y, a1, ra1, v);

        float4 xv[3];
        float s = 0.0f, sq = 0.0f;
        #pragma unroll
        for (int r = 0; r < 3; ++r) {
            float4 acc = base[r];
            #pragma unroll
            for (int k = 0; k < 9; ++k) {
                const float4 w = Wr[r][k];
                acc.x = fmaf(v[k], w.x, acc.x);
                acc.y = fmaf(v[k], w.y, acc.y);
                acc.z = fmaf(v[k], w.z, acc.z);
                acc.w = fmaf(v[k], w.w, acc.w);
            }
            xv[r] = acc;
            s  += acc.x + acc.y + acc.z + acc.w;
            sq += acc.x * acc.x + acc.y * acc.y + acc.z * acc.z + acc.w * acc.w;
        }

        #pragma unroll
        for (int off = 32; off >= 1; off >>= 1) {
            s  += __shfl_xor(s,  off, 64);
            sq += __shfl_xor(sq, off, 64);
        }
        const float mean = s * (1.0f / H);
        const float var  = sq * (1.0f / H) - mean * mean;
        const float rstd = __builtin_amdgcn_rsqf(var + LN_EPS);

        nfloat4* __restrict__ orow = outv + (size_t)box * (H / 4);
        #pragma unroll
        for (int r = 0; r < 3; ++r) {
            const float4 vx = xv[r];
            const float4 g = gm[r], be = bt[r];
            nfloat4 o;
            o.x = fmaxf(0.0f, (vx.x - mean) * rstd * g.x + be.x);
            o.y = fmaxf(0.0f, (vx.y - mean) * rstd * g.y + be.y);
            o.z = fmaxf(0.0f, (vx.z - mean) * rstd * g.z + be.z);
            o.w = fmaxf(0.0f, (vx.w - mean) * rstd * g.w + be.w);
            __builtin_nontemporal_store(o, &orow[lane + 64 * r]);
        }
    };

    int box = wid;
    for (; box + nw < N; box += 2 * nw) {
        process(box);
        process(box + nw);
    }
    if (box < N) process(box);
}

extern "C" void kernel_launch(void* const* d_in, const int* in_sizes, int n_in,
                              void* d_out, int out_size, void* d_ws, size_t ws_size,
                              hipStream_t stream) {
    const float* target = (const float*)d_in[0];
    const float* boxes  = (const float*)d_in[1];
    const float* W      = (const float*)d_in[2];
    const float* bias   = (const float*)d_in[3];
    const float* gamma  = (const float*)d_in[4];
    const float* beta   = (const float*)d_in[5];
    float* out = (float*)d_out;

    const int N = in_sizes[1] / 4;   // ocr_boxes is (N, 4)

    // ws layout (floats): [0..143] G, [144..155] row means, [160..] float2 stats
    const size_t needed = (160 + 2 * (size_t)N) * sizeof(float);
    const bool stats_ok = d_ws && ws_size >= needed && N > 0 && N <= NTRIP * 64;

    if (stats_ok) {
        float* wsf = (float*)d_ws;
        float2* stats = (float2*)(wsf + 160);

        gram_kernel<<<90, 256, 0, stream>>>(W, bias, wsf);

        int blocksA2 = (N + 255) / 256;
        if (blocksA2 > 2048) blocksA2 = 2048;
        stats_kernel<<<blocksA2, 256, 0, stream>>>(target, boxes, wsf, stats, N);

        // 1536 blocks x 4 waves = 6144 waves = 2048 trips x 3 roles
        geo_ln_main<<<1536, 256, 0, stream>>>(target, boxes, W, bias, gamma, beta,
                                              stats, out, N);
    } else {
        geo_ln_fallback<<<512, 256, 0, stream>>>(target, boxes, W, bias, gamma, beta,
                                                 out, N);
    }
}